// Round 1
// baseline (260.777 us; speedup 1.0000x reference)
//
#include <hip/hip_runtime.h>
#include <stdint.h>
#include <stddef.h>

typedef _Float16 half_t;
typedef __attribute__((ext_vector_type(8))) _Float16 f16x8;
typedef __attribute__((ext_vector_type(4))) float f32x4;

#define EPSF 1.1920928955078125e-07f

#define AS1 __attribute__((address_space(1)))
#define AS3 __attribute__((address_space(3)))

// workspace layout (offsets in half elements)
#define WS_XN   0u          // [8192][512]   normalized tokens, fp16
#define WS_WQT  4194304u    // [1536][512]   w_qkv^T fp16
#define WS_WOT  4980736u    // [512][512]    w_out^T fp16
#define WS_Q    5242880u    // [16][4096][64]
#define WS_K    9437184u    // [16][4096][64]
#define WS_VT   13631488u   // [16][64][4096]  V transposed
#define WS_AO   17825792u   // [8192][512]   attention output fp16
#define WS_NEED_BYTES 44040192u

__device__ __forceinline__ void gload16(const void* g, void* l) {
  __builtin_amdgcn_global_load_lds((const AS1 void*)g, (AS3 void*)l, 16, 0, 0);
}

// ---------------- RMSNorm + fp16 cast ----------------
__global__ __launch_bounds__(256) void k_rmsnorm(const float* __restrict__ t,
                                                 const float* __restrict__ w,
                                                 half_t* __restrict__ xn) {
  int row = blockIdx.x * 4 + (threadIdx.x >> 6);
  int ln = threadIdx.x & 63;
  const float* src = t + (size_t)row * 512 + ln * 8;
  float4 a = *(const float4*)src;
  float4 b = *(const float4*)(src + 4);
  float ss = a.x * a.x + a.y * a.y + a.z * a.z + a.w * a.w
           + b.x * b.x + b.y * b.y + b.z * b.z + b.w * b.w;
#pragma unroll
  for (int m = 32; m >= 1; m >>= 1) ss += __shfl_xor(ss, m);
  float r = rsqrtf(ss * (1.0f / 512.0f) + EPSF);
  const float* wp = w + ln * 8;
  float4 w0 = *(const float4*)wp;
  float4 w1 = *(const float4*)(wp + 4);
  f16x8 o;
  o[0] = (_Float16)(a.x * r * w0.x);
  o[1] = (_Float16)(a.y * r * w0.y);
  o[2] = (_Float16)(a.z * r * w0.z);
  o[3] = (_Float16)(a.w * r * w0.w);
  o[4] = (_Float16)(b.x * r * w1.x);
  o[5] = (_Float16)(b.y * r * w1.y);
  o[6] = (_Float16)(b.z * r * w1.z);
  o[7] = (_Float16)(b.w * r * w1.w);
  *(f16x8*)(xn + (size_t)row * 512 + ln * 8) = o;
}

// ---------------- transpose + cast fp32->fp16: dst[n][k] = src[k][n] ----------------
__global__ void k_transpose_cast(const float* __restrict__ src, half_t* __restrict__ dst,
                                 int K, int N) {
  int idx = blockIdx.x * 256 + threadIdx.x;
  if (idx >= K * N) return;
  int n = idx / K, k = idx - n * K;
  dst[idx] = (_Float16)src[(size_t)k * N + n];
}

// ---------------- shared GEMM core: C[128][128] tile = A[M][K] @ Bt[N][K]^T ----------------
// 4 waves in 2x2 grid, each 64x64; MFMA 16x16x32 f16; LDS XOR-swizzled (row&7)<<4.
__device__ __forceinline__ void gemm_core(const half_t* __restrict__ A,
                                          const half_t* __restrict__ Bt,
                                          int m0, int n0, int Ksz,
                                          half_t* Al, half_t* Bl,
                                          f32x4 acc[4][4]) {
  int wv = threadIdx.x >> 6, ln = threadIdx.x & 63;
  int wm = (wv >> 1) << 6, wn = (wv & 1) << 6;
  for (int kt = 0; kt < Ksz; kt += 64) {
#pragma unroll
    for (int i = 0; i < 4; ++i) {
      int seg = wv * 4 + i;          // 16 segs x 8 rows = 128 rows
      int r = seg * 8 + (ln >> 3);
      int cb = ((ln & 7) * 16) ^ ((r & 7) << 4);   // pre-swizzled source col
      gload16((const char*)(A + (size_t)(m0 + r) * Ksz + kt) + cb, (char*)Al + seg * 1024);
      gload16((const char*)(Bt + (size_t)(n0 + r) * Ksz + kt) + cb, (char*)Bl + seg * 1024);
    }
    __syncthreads();
#pragma unroll
    for (int kc = 0; kc < 2; ++kc) {
      f16x8 af[4], bf[4];
#pragma unroll
      for (int mt = 0; mt < 4; ++mt) {
        int rr = wm + mt * 16 + (ln & 15);
        af[mt] = *(const f16x8*)((const char*)Al + rr * 128 +
                                 ((kc * 64 + (ln >> 4) * 16) ^ ((rr & 7) << 4)));
      }
#pragma unroll
      for (int nt = 0; nt < 4; ++nt) {
        int rr = wn + nt * 16 + (ln & 15);
        bf[nt] = *(const f16x8*)((const char*)Bl + rr * 128 +
                                 ((kc * 64 + (ln >> 4) * 16) ^ ((rr & 7) << 4)));
      }
#pragma unroll
      for (int mt = 0; mt < 4; ++mt)
#pragma unroll
        for (int nt = 0; nt < 4; ++nt)
          acc[mt][nt] = __builtin_amdgcn_mfma_f32_16x16x32_f16(af[mt], bf[nt], acc[mt][nt], 0, 0, 0);
    }
    __syncthreads();
  }
}

// ---------------- QKV GEMM: [8192,512]@[512,1536], scatter q/k/vT fp16 ----------------
__global__ __launch_bounds__(256, 2) void k_gemm_qkv(const half_t* __restrict__ A,
                                                     const half_t* __restrict__ Bt,
                                                     half_t* __restrict__ q,
                                                     half_t* __restrict__ kk,
                                                     half_t* __restrict__ vt) {
  __shared__ __align__(16) half_t Al[128 * 64];
  __shared__ __align__(16) half_t Bl[128 * 64];
  f32x4 acc[4][4];
  f32x4 z = {0.f, 0.f, 0.f, 0.f};
#pragma unroll
  for (int i = 0; i < 4; ++i)
#pragma unroll
    for (int j = 0; j < 4; ++j) acc[i][j] = z;
  int m0 = blockIdx.x * 128, n0 = blockIdx.y * 128;
  gemm_core(A, Bt, m0, n0, 512, Al, Bl, acc);
  int wv = threadIdx.x >> 6, ln = threadIdx.x & 63;
  int wm = (wv >> 1) << 6, wn = (wv & 1) << 6;
#pragma unroll
  for (int mt = 0; mt < 4; ++mt) {
#pragma unroll
    for (int nt = 0; nt < 4; ++nt) {
      int gn = n0 + wn + nt * 16 + (ln & 15);
      int qkv_i = gn >> 9;         // 0,1,2
      int h = (gn >> 6) & 7;
      int d = gn & 63;
#pragma unroll
      for (int j = 0; j < 4; ++j) {
        int gm = m0 + wm + mt * 16 + (ln >> 4) * 4 + j;   // token id
        int head = ((gm >> 12) << 3) | h;                 // b*8+h
        int n = gm & 4095;
        half_t hv = (_Float16)acc[mt][nt][j];
        if (qkv_i == 0)      q [((size_t)head * 4096 + n) * 64 + d] = hv;
        else if (qkv_i == 1) kk[((size_t)head * 4096 + n) * 64 + d] = hv;
        else                 vt[((size_t)head * 64 + d) * 4096 + n] = hv;
      }
    }
  }
}

// ---------------- out GEMM: [8192,512]@[512,512] -> fp32 d_out ----------------
__global__ __launch_bounds__(256, 2) void k_gemm_out(const half_t* __restrict__ A,
                                                     const half_t* __restrict__ Bt,
                                                     float* __restrict__ out) {
  __shared__ __align__(16) half_t Al[128 * 64];
  __shared__ __align__(16) half_t Bl[128 * 64];
  f32x4 acc[4][4];
  f32x4 z = {0.f, 0.f, 0.f, 0.f};
#pragma unroll
  for (int i = 0; i < 4; ++i)
#pragma unroll
    for (int j = 0; j < 4; ++j) acc[i][j] = z;
  int m0 = blockIdx.x * 128, n0 = blockIdx.y * 128;
  gemm_core(A, Bt, m0, n0, 512, Al, Bl, acc);
  int wv = threadIdx.x >> 6, ln = threadIdx.x & 63;
  int wm = (wv >> 1) << 6, wn = (wv & 1) << 6;
#pragma unroll
  for (int mt = 0; mt < 4; ++mt)
#pragma unroll
    for (int nt = 0; nt < 4; ++nt) {
      int gn = n0 + wn + nt * 16 + (ln & 15);
#pragma unroll
      for (int j = 0; j < 4; ++j) {
        int gm = m0 + wm + mt * 16 + (ln >> 4) * 4 + j;
        out[(size_t)gm * 512 + gn] = acc[mt][nt][j];
      }
    }
}

// ---------------- flash attention: per block = 1 head x 128 q rows ----------------
// NOTE: reference applies NO softmax scale.
__global__ __launch_bounds__(256, 2) void k_attn(const half_t* __restrict__ q,
                                                 const half_t* __restrict__ kg,
                                                 const half_t* __restrict__ vt,
                                                 half_t* __restrict__ ao) {
  __shared__ __align__(16) half_t Kl[64 * 64];
  __shared__ __align__(16) half_t Vl[64 * 64];         // V^T tile: [d][kv]
  __shared__ __align__(16) half_t Pl[4][32 * 64];      // per-wave P tile
  int wv = threadIdx.x >> 6, ln = threadIdx.x & 63;
  int head = blockIdx.y;
  int q0 = blockIdx.x * 128 + wv * 32;
  const half_t* qh = q  + (size_t)head * 4096 * 64;
  const half_t* kh = kg + (size_t)head * 4096 * 64;
  const half_t* vh = vt + (size_t)head * 64 * 4096;

  // Q fragments (held in registers for the whole kernel)
  f16x8 qf[2][2];
#pragma unroll
  for (int mt = 0; mt < 2; ++mt)
#pragma unroll
    for (int kc = 0; kc < 2; ++kc) {
      int r = q0 + mt * 16 + (ln & 15);
      qf[mt][kc] = *(const f16x8*)((const char*)qh + (size_t)r * 128 + kc * 64 + (ln >> 4) * 16);
    }

  float mrun[2][4], lrun[2][4];
  f32x4 oacc[2][4];
  f32x4 z = {0.f, 0.f, 0.f, 0.f};
#pragma unroll
  for (int mt = 0; mt < 2; ++mt)
#pragma unroll
    for (int j = 0; j < 4; ++j) { mrun[mt][j] = -1e30f; lrun[mt][j] = 0.f; }
#pragma unroll
  for (int mt = 0; mt < 2; ++mt)
#pragma unroll
    for (int dt = 0; dt < 4; ++dt) oacc[mt][dt] = z;

  for (int kv0 = 0; kv0 < 4096; kv0 += 64) {
    // stage K tile (contiguous 8KB) and V^T tile (64 rows of 128B, stride 8192B)
#pragma unroll
    for (int i = 0; i < 2; ++i) {
      int seg = wv * 2 + i;          // 8 segs x 8 rows
      int r = seg * 8 + (ln >> 3);
      int cb = ((ln & 7) * 16) ^ ((r & 7) << 4);
      gload16((const char*)kh + (size_t)(kv0 + r) * 128 + cb, (char*)Kl + seg * 1024);
      gload16((const char*)vh + (size_t)r * 8192 + (size_t)kv0 * 2 + cb, (char*)Vl + seg * 1024);
    }
    __syncthreads();

    // S = Q K^T  (16 MFMAs per wave)
    f32x4 s[2][4];
#pragma unroll
    for (int mt = 0; mt < 2; ++mt)
#pragma unroll
      for (int nt = 0; nt < 4; ++nt) s[mt][nt] = z;
#pragma unroll
    for (int kc = 0; kc < 2; ++kc) {
      f16x8 bf[4];
#pragma unroll
      for (int nt = 0; nt < 4; ++nt) {
        int rr = nt * 16 + (ln & 15);
        bf[nt] = *(const f16x8*)((const char*)Kl + rr * 128 +
                                 ((kc * 64 + (ln >> 4) * 16) ^ ((rr & 7) << 4)));
      }
#pragma unroll
      for (int mt = 0; mt < 2; ++mt)
#pragma unroll
        for (int nt = 0; nt < 4; ++nt)
          s[mt][nt] = __builtin_amdgcn_mfma_f32_16x16x32_f16(qf[mt][kc], bf[nt], s[mt][nt], 0, 0, 0);
    }

    // online softmax (rows live in 16-lane groups; butterfly over masks 1,2,4,8)
#pragma unroll
    for (int mt = 0; mt < 2; ++mt) {
      float tm[4], p[4][4], ts[4];
#pragma unroll
      for (int j = 0; j < 4; ++j)
        tm[j] = fmaxf(fmaxf(s[mt][0][j], s[mt][1][j]), fmaxf(s[mt][2][j], s[mt][3][j]));
#pragma unroll
      for (int msk = 1; msk <= 8; msk <<= 1)
#pragma unroll
        for (int j = 0; j < 4; ++j) tm[j] = fmaxf(tm[j], __shfl_xor(tm[j], msk));
#pragma unroll
      for (int j = 0; j < 4; ++j) {
        float mnew = fmaxf(mrun[mt][j], tm[j]);
        float sc = __expf(mrun[mt][j] - mnew);
        mrun[mt][j] = mnew;
        lrun[mt][j] *= sc;
#pragma unroll
        for (int dt = 0; dt < 4; ++dt) oacc[mt][dt][j] *= sc;
#pragma unroll
        for (int nt = 0; nt < 4; ++nt) p[nt][j] = __expf(s[mt][nt][j] - mnew);
      }
#pragma unroll
      for (int j = 0; j < 4; ++j) ts[j] = (p[0][j] + p[1][j]) + (p[2][j] + p[3][j]);
#pragma unroll
      for (int msk = 1; msk <= 8; msk <<= 1)
#pragma unroll
        for (int j = 0; j < 4; ++j) ts[j] += __shfl_xor(ts[j], msk);
#pragma unroll
      for (int j = 0; j < 4; ++j) lrun[mt][j] += ts[j];
      // write P to this wave's LDS tile (swizzled), C-layout -> A-layout redistribution
#pragma unroll
      for (int nt = 0; nt < 4; ++nt)
#pragma unroll
        for (int j = 0; j < 4; ++j) {
          int row = mt * 16 + (ln >> 4) * 4 + j;
          int cbyte = ((nt * 16 + (ln & 15)) * 2) ^ ((row & 7) << 4);
          *(half_t*)((char*)Pl[wv] + row * 128 + cbyte) = (_Float16)p[nt][j];
        }
    }

    // O += P @ V  (16 MFMAs per wave)
#pragma unroll
    for (int mt = 0; mt < 2; ++mt)
#pragma unroll
      for (int kc = 0; kc < 2; ++kc) {
        int pr = mt * 16 + (ln & 15);
        f16x8 pf = *(const f16x8*)((const char*)Pl[wv] + pr * 128 +
                                   ((kc * 64 + (ln >> 4) * 16) ^ ((pr & 7) << 4)));
#pragma unroll
        for (int dt = 0; dt < 4; ++dt) {
          int rr = dt * 16 + (ln & 15);
          f16x8 vf = *(const f16x8*)((const char*)Vl + rr * 128 +
                                     ((kc * 64 + (ln >> 4) * 16) ^ ((rr & 7) << 4)));
          oacc[mt][dt] = __builtin_amdgcn_mfma_f32_16x16x32_f16(pf, vf, oacc[mt][dt], 0, 0, 0);
        }
      }
    __syncthreads();
  }

  // epilogue: O/l -> attn_out [token][h*64+d] fp16
  int b = head >> 3, h = head & 7;
#pragma unroll
  for (int mt = 0; mt < 2; ++mt)
#pragma unroll
    for (int dt = 0; dt < 4; ++dt)
#pragma unroll
      for (int j = 0; j < 4; ++j) {
        int n = q0 + mt * 16 + (ln >> 4) * 4 + j;
        int d = dt * 16 + (ln & 15);
        float val = oacc[mt][dt][j] / lrun[mt][j];
        ao[((size_t)(b * 4096 + n)) * 512 + h * 64 + d] = (_Float16)val;
      }
}

extern "C" void kernel_launch(void* const* d_in, const int* in_sizes, int n_in,
                              void* d_out, int out_size, void* d_ws, size_t ws_size,
                              hipStream_t stream) {
  if (ws_size < WS_NEED_BYTES) return;  // loud failure if scratch too small
  const float* tokens = (const float*)d_in[0];
  const float* nw     = (const float*)d_in[1];
  const float* wqkv   = (const float*)d_in[2];
  const float* wout   = (const float*)d_in[3];
  float* out = (float*)d_out;
  half_t* ws = (half_t*)d_ws;
  half_t* xn  = ws + WS_XN;
  half_t* wqt = ws + WS_WQT;
  half_t* wot = ws + WS_WOT;
  half_t* qb  = ws + WS_Q;
  half_t* kb  = ws + WS_K;
  half_t* vtb = ws + WS_VT;
  half_t* aob = ws + WS_AO;

  k_rmsnorm<<<2048, 256, 0, stream>>>(tokens, nw, xn);
  k_transpose_cast<<<(1536 * 512 + 255) / 256, 256, 0, stream>>>(wqkv, wqt, 512, 1536);
  k_transpose_cast<<<(512 * 512 + 255) / 256, 256, 0, stream>>>(wout, wot, 512, 512);
  k_gemm_qkv<<<dim3(64, 12), 256, 0, stream>>>(xn, wqt, qb, kb, vtb);
  k_attn<<<dim3(32, 16), 256, 0, stream>>>(qb, kb, vtb, aob);
  k_gemm_out<<<dim3(64, 4), 256, 0, stream>>>(aob, wot, out);
}

// Round 3
// 152.879 us; speedup vs baseline: 1.7058x; 1.7058x over previous
//
#include <hip/hip_runtime.h>
#include <stdint.h>
#include <stddef.h>

typedef _Float16 half_t;
typedef __attribute__((ext_vector_type(2))) __fp16 fp16v2;
typedef __attribute__((ext_vector_type(4))) _Float16 f16x4;
typedef __attribute__((ext_vector_type(8))) _Float16 f16x8;
typedef __attribute__((ext_vector_type(4))) float f32x4;

#define EPSF 1.1920928955078125e-07f
#define LOG2E 1.4426950408889634f

#define AS1 __attribute__((address_space(1)))
#define AS3 __attribute__((address_space(3)))

// workspace layout (offsets in half elements)
#define WS_XN   0u          // [8192][512]   normalized tokens, fp16
#define WS_WQT  4194304u    // [1536][512]   w_qkv^T fp16
#define WS_WOT  4980736u    // [512][512]    w_out^T fp16
#define WS_Q    5242880u    // [16][4096][64]  (pre-scaled by log2e)
#define WS_K    9437184u    // [16][4096][64]
#define WS_VT   13631488u   // [16][64][4096]  V transposed
#define WS_AO   17825792u   // [8192][512]   attention output fp16
#define WS_NEED_BYTES 44040192u

__device__ __forceinline__ void gload16(const void* g, void* l) {
  __builtin_amdgcn_global_load_lds((const AS1 void*)g, (AS3 void*)l, 16, 0, 0);
}

__device__ __forceinline__ float fast_exp2(float x) {
#if __has_builtin(__builtin_amdgcn_exp2f)
  return __builtin_amdgcn_exp2f(x);
#else
  return exp2f(x);
#endif
}

// ---------------- RMSNorm + fp16 cast ----------------
__global__ __launch_bounds__(256) void k_rmsnorm(const float* __restrict__ t,
                                                 const float* __restrict__ w,
                                                 half_t* __restrict__ xn) {
  int row = blockIdx.x * 4 + (threadIdx.x >> 6);
  int ln = threadIdx.x & 63;
  const float* src = t + (size_t)row * 512 + ln * 8;
  float4 a = *(const float4*)src;
  float4 b = *(const float4*)(src + 4);
  float ss = a.x * a.x + a.y * a.y + a.z * a.z + a.w * a.w
           + b.x * b.x + b.y * b.y + b.z * b.z + b.w * b.w;
#pragma unroll
  for (int m = 32; m >= 1; m >>= 1) ss += __shfl_xor(ss, m);
  float r = rsqrtf(ss * (1.0f / 512.0f) + EPSF);
  const float* wp = w + ln * 8;
  float4 w0 = *(const float4*)wp;
  float4 w1 = *(const float4*)(wp + 4);
  f16x8 o;
  o[0] = (_Float16)(a.x * r * w0.x);
  o[1] = (_Float16)(a.y * r * w0.y);
  o[2] = (_Float16)(a.z * r * w0.z);
  o[3] = (_Float16)(a.w * r * w0.w);
  o[4] = (_Float16)(b.x * r * w1.x);
  o[5] = (_Float16)(b.y * r * w1.y);
  o[6] = (_Float16)(b.z * r * w1.z);
  o[7] = (_Float16)(b.w * r * w1.w);
  *(f16x8*)(xn + (size_t)row * 512 + ln * 8) = o;
}

// ---------------- transpose + cast fp32->fp16: dst[n][k] = src[k][n] ----------------
__global__ void k_transpose_cast(const float* __restrict__ src, half_t* __restrict__ dst,
                                 int K, int N) {
  int idx = blockIdx.x * 256 + threadIdx.x;
  if (idx >= K * N) return;
  int n = idx / K, k = idx - n * K;
  dst[idx] = (_Float16)src[(size_t)k * N + n];
}

// ---------------- shared GEMM core: C[128][128] tile = A[M][K] @ Bt[N][K]^T ----------------
__device__ __forceinline__ void gemm_core(const half_t* __restrict__ A,
                                          const half_t* __restrict__ Bt,
                                          int m0, int n0, int Ksz,
                                          half_t* Al, half_t* Bl,
                                          f32x4 acc[4][4]) {
  int wv = threadIdx.x >> 6, ln = threadIdx.x & 63;
  int wm = (wv >> 1) << 6, wn = (wv & 1) << 6;
  for (int kt = 0; kt < Ksz; kt += 64) {
#pragma unroll
    for (int i = 0; i < 4; ++i) {
      int seg = wv * 4 + i;          // 16 segs x 8 rows = 128 rows
      int r = seg * 8 + (ln >> 3);
      int cb = ((ln & 7) * 16) ^ ((r & 7) << 4);   // pre-swizzled source col
      gload16((const char*)(A + (size_t)(m0 + r) * Ksz + kt) + cb, (char*)Al + seg * 1024);
      gload16((const char*)(Bt + (size_t)(n0 + r) * Ksz + kt) + cb, (char*)Bl + seg * 1024);
    }
    __syncthreads();
#pragma unroll
    for (int kc = 0; kc < 2; ++kc) {
      f16x8 af[4], bf[4];
#pragma unroll
      for (int mt = 0; mt < 4; ++mt) {
        int rr = wm + mt * 16 + (ln & 15);
        af[mt] = *(const f16x8*)((const char*)Al + rr * 128 +
                                 ((kc * 64 + (ln >> 4) * 16) ^ ((rr & 7) << 4)));
      }
#pragma unroll
      for (int nt = 0; nt < 4; ++nt) {
        int rr = wn + nt * 16 + (ln & 15);
        bf[nt] = *(const f16x8*)((const char*)Bl + rr * 128 +
                                 ((kc * 64 + (ln >> 4) * 16) ^ ((rr & 7) << 4)));
      }
#pragma unroll
      for (int mt = 0; mt < 4; ++mt)
#pragma unroll
        for (int nt = 0; nt < 4; ++nt)
          acc[mt][nt] = __builtin_amdgcn_mfma_f32_16x16x32_f16(af[mt], bf[nt], acc[mt][nt], 0, 0, 0);
    }
    __syncthreads();
  }
}

// ---------------- QKV GEMM: scatter q (log2e-scaled) / k / vT fp16 ----------------
__global__ __launch_bounds__(256, 2) void k_gemm_qkv(const half_t* __restrict__ A,
                                                     const half_t* __restrict__ Bt,
                                                     half_t* __restrict__ q,
                                                     half_t* __restrict__ kk,
                                                     half_t* __restrict__ vt) {
  __shared__ __align__(16) half_t Al[128 * 64];
  __shared__ __align__(16) half_t Bl[128 * 64];
  f32x4 acc[4][4];
  f32x4 z = {0.f, 0.f, 0.f, 0.f};
#pragma unroll
  for (int i = 0; i < 4; ++i)
#pragma unroll
    for (int j = 0; j < 4; ++j) acc[i][j] = z;
  int m0 = blockIdx.x * 128, n0 = blockIdx.y * 128;
  gemm_core(A, Bt, m0, n0, 512, Al, Bl, acc);
  int wv = threadIdx.x >> 6, ln = threadIdx.x & 63;
  int wm = (wv >> 1) << 6, wn = (wv & 1) << 6;
#pragma unroll
  for (int mt = 0; mt < 4; ++mt) {
#pragma unroll
    for (int nt = 0; nt < 4; ++nt) {
      int gn = n0 + wn + nt * 16 + (ln & 15);
      int qkv_i = gn >> 9;         // 0,1,2
      int h = (gn >> 6) & 7;
      int d = gn & 63;
#pragma unroll
      for (int j = 0; j < 4; ++j) {
        int gm = m0 + wm + mt * 16 + (ln >> 4) * 4 + j;   // token id
        int head = ((gm >> 12) << 3) | h;                 // b*8+h
        int n = gm & 4095;
        float av = acc[mt][nt][j];
        if (qkv_i == 0)      q [((size_t)head * 4096 + n) * 64 + d] = (_Float16)(av * LOG2E);
        else if (qkv_i == 1) kk[((size_t)head * 4096 + n) * 64 + d] = (_Float16)av;
        else                 vt[((size_t)head * 64 + d) * 4096 + n] = (_Float16)av;
      }
    }
  }
}

// ---------------- out GEMM: [8192,512]@[512,512] -> fp32 d_out ----------------
__global__ __launch_bounds__(256, 2) void k_gemm_out(const half_t* __restrict__ A,
                                                     const half_t* __restrict__ Bt,
                                                     float* __restrict__ out) {
  __shared__ __align__(16) half_t Al[128 * 64];
  __shared__ __align__(16) half_t Bl[128 * 64];
  f32x4 acc[4][4];
  f32x4 z = {0.f, 0.f, 0.f, 0.f};
#pragma unroll
  for (int i = 0; i < 4; ++i)
#pragma unroll
    for (int j = 0; j < 4; ++j) acc[i][j] = z;
  int m0 = blockIdx.x * 128, n0 = blockIdx.y * 128;
  gemm_core(A, Bt, m0, n0, 512, Al, Bl, acc);
  int wv = threadIdx.x >> 6, ln = threadIdx.x & 63;
  int wm = (wv >> 1) << 6, wn = (wv & 1) << 6;
#pragma unroll
  for (int mt = 0; mt < 4; ++mt)
#pragma unroll
    for (int nt = 0; nt < 4; ++nt) {
      int gn = n0 + wn + nt * 16 + (ln & 15);
#pragma unroll
      for (int j = 0; j < 4; ++j) {
        int gm = m0 + wm + mt * 16 + (ln >> 4) * 4 + j;
        out[(size_t)gm * 512 + gn] = acc[mt][nt][j];
      }
    }
}

// ---------------- flash attention, swapped-operand, in-register softmax ----------------
// block = 1 head x 128 q-rows, 4 waves x 32 q-rows. KVBLK=64, double-buffered K/V in LDS.
// S^T = mfma(K, Q): lane's q = ln&15 (per mt), kv spread over (ln>>4) groups.
// O^T = mfma(V^T, P^T) with matching custom k-slot permutation on both operands.
__global__ __launch_bounds__(256, 2) void k_attn(const half_t* __restrict__ q,
                                                 const half_t* __restrict__ kg,
                                                 const half_t* __restrict__ vt,
                                                 half_t* __restrict__ ao) {
  __shared__ __align__(16) char lds[32768];   // [2 bufs][K 8KB | V^T 8KB]
  const int wv = threadIdx.x >> 6, ln = threadIdx.x & 63;
  const int bid = blockIdx.x;
  const int lin = (bid & 7) * 64 + (bid >> 3);   // XCD-chunk swizzle (512 = 8*64)
  const int head = lin >> 5;
  const int qt = lin & 31;
  const int q0 = qt * 128 + wv * 32;
  const char* qh = (const char*)(q  + (size_t)head * 4096 * 64);
  const char* kh = (const char*)(kg + (size_t)head * 4096 * 64);
  const char* vh = (const char*)(vt + (size_t)head * 64 * 4096);

  // Q fragments (B-operand: col = q-row = ln&15, k-slots = d)
  f16x8 qf[2][2];
#pragma unroll
  for (int mt = 0; mt < 2; ++mt)
#pragma unroll
    for (int kc = 0; kc < 2; ++kc) {
      int r = q0 + mt * 16 + (ln & 15);
      qf[mt][kc] = *(const f16x8*)(qh + (size_t)r * 128 + kc * 64 + (ln >> 4) * 16);
    }

  // staging source pointers (advance per tile); pre-swizzled global source
  const char* ks[2]; const char* vs[2]; int lo[2];
#pragma unroll
  for (int i = 0; i < 2; ++i) {
    int seg = wv * 2 + i;
    int r = seg * 8 + (ln >> 3);
    int cb = ((ln & 7) * 16) ^ ((r & 7) << 4);
    ks[i] = kh + (size_t)r * 128 + cb;
    vs[i] = vh + (size_t)r * 8192 + cb;
    lo[i] = seg * 1024;
  }

  float mrun[2] = {-1e30f, -1e30f};
  float lsum[2] = {0.f, 0.f};
  f32x4 oacc[2][4];
  const f32x4 z = {0.f, 0.f, 0.f, 0.f};
#pragma unroll
  for (int mt = 0; mt < 2; ++mt)
#pragma unroll
    for (int dt = 0; dt < 4; ++dt) oacc[mt][dt] = z;

  // prologue: stage tile 0 into buf 0
  {
    char* base = lds;
    gload16(ks[0], base + lo[0]); gload16(ks[1], base + lo[1]);
    gload16(vs[0], base + 8192 + lo[0]); gload16(vs[1], base + 8192 + lo[1]);
    ks[0] += 8192; ks[1] += 8192; vs[0] += 128; vs[1] += 128;
  }
  __syncthreads();

  int cur = 0;
#pragma unroll 1
  for (int t = 0; t < 64; ++t) {
    if (t < 63) {   // issue next-tile prefetch first; lands during compute
      char* base = lds + (cur ^ 1) * 16384;
      gload16(ks[0], base + lo[0]); gload16(ks[1], base + lo[1]);
      gload16(vs[0], base + 8192 + lo[0]); gload16(vs[1], base + 8192 + lo[1]);
      ks[0] += 8192; ks[1] += 8192; vs[0] += 128; vs[1] += 128;
    }
    const char* Kb = lds + cur * 16384;
    const char* Vb = Kb + 8192;

    // S^T = K · Q^T  : C[row=kv][col=q]
    f32x4 s[2][4];
#pragma unroll
    for (int mt = 0; mt < 2; ++mt)
#pragma unroll
      for (int kt = 0; kt < 4; ++kt) s[mt][kt] = z;
    __builtin_amdgcn_s_setprio(1);
#pragma unroll
    for (int kc = 0; kc < 2; ++kc) {
      f16x8 kf[4];
#pragma unroll
      for (int kt = 0; kt < 4; ++kt) {
        int rr = kt * 16 + (ln & 15);
        kf[kt] = *(const f16x8*)(Kb + rr * 128 + ((kc * 64 + (ln >> 4) * 16) ^ ((rr & 7) << 4)));
      }
#pragma unroll
      for (int mt = 0; mt < 2; ++mt)
#pragma unroll
        for (int kt = 0; kt < 4; ++kt)
          s[mt][kt] = __builtin_amdgcn_mfma_f32_16x16x32_f16(kf[kt], qf[mt][kc], s[mt][kt], 0, 0, 0);
    }
    __builtin_amdgcn_s_setprio(0);

    // online softmax in log2 domain (Q pre-scaled by log2e); one q per lane per mt
    f16x8 pf[2][2];
#pragma unroll
    for (int mt = 0; mt < 2; ++mt) {
      float a0 = fmaxf(fmaxf(s[mt][0][0], s[mt][0][1]), fmaxf(s[mt][0][2], s[mt][0][3]));
      float a1 = fmaxf(fmaxf(s[mt][1][0], s[mt][1][1]), fmaxf(s[mt][1][2], s[mt][1][3]));
      float a2 = fmaxf(fmaxf(s[mt][2][0], s[mt][2][1]), fmaxf(s[mt][2][2], s[mt][2][3]));
      float a3 = fmaxf(fmaxf(s[mt][3][0], s[mt][3][1]), fmaxf(s[mt][3][2], s[mt][3][3]));
      float tm = fmaxf(fmaxf(a0, a1), fmaxf(a2, a3));
      tm = fmaxf(tm, __shfl_xor(tm, 16));
      tm = fmaxf(tm, __shfl_xor(tm, 32));
      if (__any(tm > mrun[mt] + 11.0f)) {    // defer-max: skip rescale when within margin
        float mnew = fmaxf(mrun[mt], tm);
        float sc = fast_exp2(mrun[mt] - mnew);
        mrun[mt] = mnew;
        lsum[mt] *= sc;
#pragma unroll
        for (int dt = 0; dt < 4; ++dt) {
          oacc[mt][dt][0] *= sc; oacc[mt][dt][1] *= sc;
          oacc[mt][dt][2] *= sc; oacc[mt][dt][3] *= sc;
        }
      }
      float p[4][4];
#pragma unroll
      for (int kt = 0; kt < 4; ++kt)
#pragma unroll
        for (int r = 0; r < 4; ++r) p[kt][r] = fast_exp2(s[mt][kt][r] - mrun[mt]);
      float ps = 0.f;
#pragma unroll
      for (int kt = 0; kt < 4; ++kt)
        ps += (p[kt][0] + p[kt][1]) + (p[kt][2] + p[kt][3]);
      lsum[mt] += ps;
#pragma unroll
      for (int kc = 0; kc < 2; ++kc) {
        union { f16x8 v; fp16v2 h[4]; } u;
        u.h[0] = __builtin_amdgcn_cvt_pkrtz(p[2 * kc][0], p[2 * kc][1]);
        u.h[1] = __builtin_amdgcn_cvt_pkrtz(p[2 * kc][2], p[2 * kc][3]);
        u.h[2] = __builtin_amdgcn_cvt_pkrtz(p[2 * kc + 1][0], p[2 * kc + 1][1]);
        u.h[3] = __builtin_amdgcn_cvt_pkrtz(p[2 * kc + 1][2], p[2 * kc + 1][3]);
        pf[mt][kc] = u.v;
      }
    }

    // O^T += V^T · P^T : C[row=d][col=q]; custom (same) k-slot map on A and B
    __builtin_amdgcn_s_setprio(1);
#pragma unroll
    for (int kc = 0; kc < 2; ++kc)
#pragma unroll
      for (int dt = 0; dt < 4; ++dt) {
        int rr = dt * 16 + (ln & 15);
        int sw = (rr & 7) << 4;
        f16x4 vlo = *(const f16x4*)(Vb + rr * 128 + ((kc * 64 + (ln >> 4) * 8) ^ sw));
        f16x4 vhi = *(const f16x4*)(Vb + rr * 128 + ((kc * 64 + 32 + (ln >> 4) * 8) ^ sw));
        f16x8 vf = __builtin_shufflevector(vlo, vhi, 0, 1, 2, 3, 4, 5, 6, 7);
#pragma unroll
        for (int mt = 0; mt < 2; ++mt)
          oacc[mt][dt] = __builtin_amdgcn_mfma_f32_16x16x32_f16(vf, pf[mt][kc], oacc[mt][dt], 0, 0, 0);
      }
    __builtin_amdgcn_s_setprio(0);

    __syncthreads();   // drains vmcnt (prefetch had full compute phase to land)
    cur ^= 1;
  }

  // epilogue: O^T/l -> attn_out [token][h*64+d] fp16
  const int b = head >> 3, h = head & 7;
#pragma unroll
  for (int mt = 0; mt < 2; ++mt) {
    float l = lsum[mt];
    l += __shfl_xor(l, 16);
    l += __shfl_xor(l, 32);
    float inv = 1.0f / l;
    int n = q0 + mt * 16 + (ln & 15);
    half_t* dst = ao + ((size_t)(b * 4096 + n)) * 512 + h * 64 + (ln >> 4) * 4;
#pragma unroll
    for (int dt = 0; dt < 4; ++dt) {
      f16x4 o4;
      o4[0] = (_Float16)(oacc[mt][dt][0] * inv);
      o4[1] = (_Float16)(oacc[mt][dt][1] * inv);
      o4[2] = (_Float16)(oacc[mt][dt][2] * inv);
      o4[3] = (_Float16)(oacc[mt][dt][3] * inv);
      *(f16x4*)(dst + dt * 16) = o4;
    }
  }
}

extern "C" void kernel_launch(void* const* d_in, const int* in_sizes, int n_in,
                              void* d_out, int out_size, void* d_ws, size_t ws_size,
                              hipStream_t stream) {
  if (ws_size < WS_NEED_BYTES) return;  // loud failure if scratch too small
  const float* tokens = (const float*)d_in[0];
  const float* nw     = (const float*)d_in[1];
  const float* wqkv   = (const float*)d_in[2];
  const float* wout   = (const float*)d_in[3];
  float* out = (float*)d_out;
  half_t* ws = (half_t*)d_ws;
  half_t* xn  = ws + WS_XN;
  half_t* wqt = ws + WS_WQT;
  half_t* wot = ws + WS_WOT;
  half_t* qb  = ws + WS_Q;
  half_t* kb  = ws + WS_K;
  half_t* vtb = ws + WS_VT;
  half_t* aob = ws + WS_AO;

  k_rmsnorm<<<2048, 256, 0, stream>>>(tokens, nw, xn);
  k_transpose_cast<<<(1536 * 512 + 255) / 256, 256, 0, stream>>>(wqkv, wqt, 512, 1536);
  k_transpose_cast<<<(512 * 512 + 255) / 256, 256, 0, stream>>>(wqkv ? wout : wout, wot, 512, 512);
  k_gemm_qkv<<<dim3(64, 12), 256, 0, stream>>>(xn, wqt, qb, kb, vtb);
  k_attn<<<512, 256, 0, stream>>>(qb, kb, vtb, aob);
  k_gemm_out<<<dim3(64, 4), 256, 0, stream>>>(aob, wot, out);
}